// Round 9
// baseline (123.355 us; speedup 1.0000x reference)
//
#include <hip/hip_runtime.h>

// Problem: 2048x2048 image, P Gaussian peaks splatted into (ws x ws) windows
// at rounded integer centers + 0.1 background. ws = int(5*max(width)) odd-adj.
//
// R7/R8: separability -> per-64x64-region GEMM C[r][c]=sum_k A[k][r]*B[k][c]
// (mfma_f32_16x16x32_f16), factors zero outside window; no atomics in render.
// R9: kill render's staging fat. k_bin now appends each peak directly into
// the candidate list of every 64x64 region its window overlaps (1-4 regions,
// exact test using device-computed half) -> render staging is ONE coalesced
// round of <=CAPR float4 loads, no filtering/ballot/compaction. k_prep (one
// block) computes wmax and zeroes the 1024 region counters (replaces memset).
// Harness floor ~88us (268MB ws 0xAA re-poison fill alone = 43us @ 6.2TB/s).

#define IMG_W 2048
#define IMG_H 2048
#define REG 64                  // region edge (px), one block per region
#define NREG_X (IMG_W / REG)    // 32
#define NREG (NREG_X * NREG_X)  // 1024
#define CAPR 160                // slots/region; lambda~86, +8 sigma
#define CH 32                   // K-chunk per MFMA step
#define CH_PAD 40               // f16 row stride: 80 B -> b128-aligned rows

typedef _Float16 half8 __attribute__((ext_vector_type(8)));
typedef float floatx4 __attribute__((ext_vector_type(4)));

// One block: global width max (for window size) + zero region counters.
__global__ __launch_bounds__(1024) void k_prep(const float* __restrict__ wd, int P,
                                               unsigned int* __restrict__ wmax,
                                               int* __restrict__ rcounts) {
    __shared__ float sred[16];
    int t = threadIdx.x;
    float m = 0.0f;                          // widths > 0; 0 is identity
    for (int i = t; i < P; i += 1024) m = fmaxf(m, wd[i]);
    for (int s = 32; s >= 1; s >>= 1) m = fmaxf(m, __shfl_xor(m, s));
    if ((t & 63) == 0) sred[t >> 6] = m;
    __syncthreads();
    if (t < 16) {
        float v = sred[t];
        for (int s = 8; s >= 1; s >>= 1) v = fmaxf(v, __shfl_xor(v, s));
        if (t == 0) *wmax = __float_as_uint(v);
    }
    if (t < NREG) rcounts[t] = 0;
}

// Append each peak to every region its (2*half+1)-window overlaps (1-4).
__global__ void k_bin(const float* __restrict__ px, const float* __restrict__ py,
                      const float* __restrict__ ht, const float* __restrict__ wd,
                      int P, const unsigned int* __restrict__ wmax,
                      int* __restrict__ rcounts, float4* __restrict__ rbins) {
    int i = blockIdx.x * blockDim.x + threadIdx.x;
    if (i >= P) return;
    float wm = __uint_as_float(*wmax);
    int wsz = (int)(5.0 * (double)wm);       // int(5*float(max_w)), exact in dbl
    if ((wsz & 1) == 0) wsz++;
    int half = wsz >> 1;

    float cxf = rintf(px[i]);                // rintf = round-half-even = jnp.round
    float cyf = rintf(py[i]);
    int cxi = (int)cxf, cyi = (int)cyf;
    float w = wd[i];
    float4 rec = make_float4(cxf, cyf, ht[i], -0.5f / (w * w));

    int rx0 = max(0, (cxi - half) >> 6), rx1 = min(NREG_X - 1, (cxi + half) >> 6);
    int ry0 = max(0, (cyi - half) >> 6), ry1 = min(NREG_X - 1, (cyi + half) >> 6);
    for (int ry = ry0; ry <= ry1; ++ry)
        for (int rx = rx0; rx <= rx1; ++rx) {
            int r = ry * NREG_X + rx;
            int slot = atomicAdd(&rcounts[r], 1);
            if (slot < CAPR) rbins[(size_t)r * CAPR + slot] = rec;
        }
}

__global__ __launch_bounds__(512) void k_render(
    const int* __restrict__ rcounts, const float4* __restrict__ rbins,
    const unsigned int* __restrict__ wmax, float* __restrict__ out)
{
    __shared__ _Float16 Afb[2][REG * CH_PAD];   // [r][k] row factors, dbuf
    __shared__ _Float16 Bfb[2][REG * CH_PAD];   // [c][k] col factors, dbuf
    __shared__ float4 cand[CAPR];               // staged candidates (2560 B)

    int flat = threadIdx.x;
    int wave = flat >> 6;
    int lane = flat & 63;

    // window half-size, exactly as reference: int(5*float64(max_w)), odd-adj.
    float wm = __uint_as_float(*wmax);
    int wsz = (int)(5.0 * (double)wm);
    if ((wsz & 1) == 0) wsz++;
    int half = wsz >> 1;
    float halff = (float)half;

    int RX0 = blockIdx.x * REG;
    int RY0 = blockIdx.y * REG;
    int region = blockIdx.y * NREG_X + blockIdx.x;

    // ---- stage: one coalesced round, no filtering (lists are exact) ----
    int nc = min(rcounts[region], CAPR);
    if (flat < nc) cand[flat] = rbins[(size_t)region * CAPR + flat];
    __syncthreads();
    int nch = (nc + CH - 1) / CH;

    // ---- K-chunked GEMM: C[r][c] = sum_k Af[r][k]*Bf[c][k] ----
    // wave handles output tiles t=wave and t+8: m-off=(t&3)*16, n-off=(t>>2)*16.
    // mfma_f32_16x16x32_f16 frags: A[m=lane&15][k=quad*8+j],
    // B[k=quad*8+j][n=lane&15]; C/D: col=lane&15, row=quad*4+reg.
    floatx4 acc0 = {0.f, 0.f, 0.f, 0.f};
    floatx4 acc1 = {0.f, 0.f, 0.f, 0.f};
    int m0 = (wave & 3) * 16,       n0 = (wave >> 2) * 16;
    int m1 = ((wave + 8) & 3) * 16, n1 = ((wave + 8) >> 2) * 16;
    int fr = lane & 15;             // frag spatial index
    int fk = (lane >> 4) * 8;       // frag k offset

    // build roles: waves 0-3 -> A (rows/y), waves 4-7 -> B (cols/x);
    // octet = wave&3 covers k sub-range [oct*8, oct*8+8). Lane owns spatial
    // coord `lane`; computes 8 k-values in regs, ONE ds_write_b128.
    int side = wave >> 2;           // 0 = A, 1 = B
    int oct = wave & 3;
    float dbase = (side ? (float)RX0 : (float)RY0) + (float)lane;

    for (int ci = 0; ci < nch; ++ci) {
        int b = ci & 1;
        int c0 = ci * CH + oct * 8;
        half8 hv;
        #pragma unroll
        for (int t = 0; t < 8; ++t) {
            int k = c0 + t;
            float val = 0.0f;
            if (k < nc) {
                float4 p = cand[k];              // wave-uniform -> broadcast
                float d = dbase - (side ? p.x : p.y);
                if (fabsf(d) <= halff) {
                    val = __expf(p.w * d * d);
                    if (side) val *= p.z;        // fold height into B
                }
            }
            hv[t] = (_Float16)val;
        }
        _Float16* dst = side ? &Bfb[b][lane * CH_PAD + oct * 8]
                             : &Afb[b][lane * CH_PAD + oct * 8];
        *(half8*)dst = hv;                       // 16 B aligned (80B rows)
        __syncthreads();                         // build(ci) -> mfma(ci); also
                                                 // fences mfma(ci-1) vs
                                                 // build(ci+1) buffer reuse
        half8 a0 = *(const half8*)&Afb[b][(m0 + fr) * CH_PAD + fk];
        half8 b0 = *(const half8*)&Bfb[b][(n0 + fr) * CH_PAD + fk];
        acc0 = __builtin_amdgcn_mfma_f32_16x16x32_f16(a0, b0, acc0, 0, 0, 0);
        half8 a1 = *(const half8*)&Afb[b][(m1 + fr) * CH_PAD + fk];
        half8 b1 = *(const half8*)&Bfb[b][(n1 + fr) * CH_PAD + fk];
        acc1 = __builtin_amdgcn_mfma_f32_16x16x32_f16(a1, b1, acc1, 0, 0, 0);
    }

    // ---- epilogue: background + store (C/D layout: col=lane&15, row=q*4+reg)
    int col = lane & 15;
    int qr = (lane >> 4) * 4;
    {
        size_t gx = (size_t)(RX0 + n0 + col);
        size_t gy = (size_t)(RY0 + m0 + qr);
        for (int r = 0; r < 4; ++r)
            out[(gy + r) * IMG_W + gx] = acc0[r] + 0.1f;
    }
    {
        size_t gx = (size_t)(RX0 + n1 + col);
        size_t gy = (size_t)(RY0 + m1 + qr);
        for (int r = 0; r < 4; ++r)
            out[(gy + r) * IMG_W + gx] = acc1[r] + 0.1f;
    }
}

extern "C" void kernel_launch(void* const* d_in, const int* in_sizes, int n_in,
                              void* d_out, int out_size, void* d_ws, size_t ws_size,
                              hipStream_t stream) {
    // inputs: 0:X 1:Y 2:pos_x 3:pos_y 4:height 5:width (X/Y unused: X[0,0]=Y[0,0]=0)
    const float* pos_x  = (const float*)d_in[2];
    const float* pos_y  = (const float*)d_in[3];
    const float* height = (const float*)d_in[4];
    const float* width  = (const float*)d_in[5];
    int P = in_sizes[2];
    float* out = (float*)d_out;
    char* ws = (char*)d_ws;

    // layout: [wmax pad16 | rcounts NREG | rbins NREG*CAPR*16]  (~2.7 MB)
    unsigned int* wmax = (unsigned int*)ws;
    int* rcounts = (int*)(ws + 16);
    size_t rbins_off = (16 + sizeof(int) * (size_t)NREG + 15) & ~(size_t)15;
    float4* rbins = (float4*)(ws + rbins_off);

    k_prep<<<1, 1024, 0, stream>>>(width, P, wmax, rcounts);
    k_bin<<<(P + 255) / 256, 256, 0, stream>>>(pos_x, pos_y, height, width, P,
                                               wmax, rcounts, rbins);
    dim3 grid(NREG_X, NREG_X), block(512);
    k_render<<<grid, block, 0, stream>>>(rcounts, rbins, wmax, out);
}

// Round 10
// 106.835 us; speedup vs baseline: 1.1546x; 1.1546x over previous
//
#include <hip/hip_runtime.h>

// Problem: 2048x2048 image, P Gaussian peaks splatted into (ws x ws) windows
// at rounded integer centers + 0.1 background. ws = int(5*max(width)) odd-adj.
//
// R7/R8 (best, 105.7us): separability -> per-64x64-region GEMM
// C[r][c] = sum_k A[k][r]*B[k][c] via mfma_f32_16x16x32_f16; factors zeroed
// outside the window; no atomics in render; double-buffered factor build with
// one ds_write_b128 per lane per chunk.
// R9 (regressed, 123.4us): single-block wmax prep = ~9us single-CU HBM stall
// serialized before binning. LESSON: never single-block a device-wide
// reduction in the dependency chain; R8's in-k_bin wave-reduce+atomicMax is
// near-free (R2: same-address atomics are cheap).
// R10 = R8 revert + one fix: stage the 36 cell counts into LDS once (merged
// into the existing barrier) instead of 720 redundant dependent global loads.
//
// Harness floor ~90us (268MB ws 0xAA re-poison fill alone = 43us @ 6.2TB/s);
// controllable kernel work ~16us. Practical ceiling ~100us.

#define IMG_W 2048
#define IMG_H 2048
#define CELL_SHIFT 4            // 16-px cells
#define CELLS_X 128
#define NCELL (CELLS_X * CELLS_X)
#define CAP 20                  // slots/cell; lambda=3.05, P(any overflow)~1e-6
#define REG 64                  // region edge (px), one block per region
#define CH 32                   // K-chunk per MFMA step
#define CH_PAD 40               // f16 row stride: 80 B -> b128-aligned rows
#define CANDMAX 256             // region K ~ Poisson(80); 256 = +19 sigma
#define MAXCELLS 36             // max 6x6 cells overlap a 64px region (+/-half)

typedef _Float16 half8 __attribute__((ext_vector_type(8)));
typedef float floatx4 __attribute__((ext_vector_type(4)));

// Fused: count into CAP bins + global width max (one pass, no scan needed).
__global__ void k_bin(const float* __restrict__ px, const float* __restrict__ py,
                      const float* __restrict__ ht, const float* __restrict__ wd,
                      int P, int* __restrict__ counts, unsigned int* __restrict__ wmax,
                      float4* __restrict__ bins) {
    int i = blockIdx.x * blockDim.x + threadIdx.x;
    bool live = (i < P);
    float w = live ? wd[i] : 0.0f;          // widths > 0; 0 is identity for max
    float wr = w;
    for (int m = 32; m >= 1; m >>= 1)
        wr = fmaxf(wr, __shfl_xor(wr, m));
    if ((threadIdx.x & 63) == 0)
        atomicMax(wmax, __float_as_uint(wr)); // positive floats: bit order == order
    if (!live) return;
    float cxf = rintf(px[i]);               // rintf = round-half-even = jnp.round
    float cyf = rintf(py[i]);
    int cell = (((int)cyf) >> CELL_SHIFT) * CELLS_X + (((int)cxf) >> CELL_SHIFT);
    int slot = atomicAdd(&counts[cell], 1);
    if (slot < CAP)
        bins[(size_t)cell * CAP + slot] = make_float4(cxf, cyf, ht[i], -0.5f / (w * w));
}

__global__ __launch_bounds__(512) void k_render(
    const int* __restrict__ counts, const float4* __restrict__ bins,
    const unsigned int* __restrict__ wmax, float* __restrict__ out)
{
    __shared__ _Float16 Afb[2][REG * CH_PAD];   // [r][k] row factors, dbuf
    __shared__ _Float16 Bfb[2][REG * CH_PAD];   // [c][k] col factors, dbuf
    __shared__ float4 cand[CANDMAX];            // staged candidates (4096 B)
    __shared__ int scnt[MAXCELLS];              // per-cell counts (LDS-cached)
    __shared__ int ncand_sh;

    int flat = threadIdx.x;
    int wave = flat >> 6;
    int lane = flat & 63;

    // window half-size, exactly as reference: int(5*float64(max_w)), odd-adj.
    float wm = __uint_as_float(*wmax);
    int wsz = (int)(5.0 * (double)wm);
    if ((wsz & 1) == 0) wsz++;
    int half = wsz >> 1;
    float halff = (float)half;

    int RX0 = blockIdx.x * REG;
    int RY0 = blockIdx.y * REG;

    // ---- stage setup: cell window + LDS count cache (one barrier) ----
    int cx0 = max(0, (RX0 - half) >> CELL_SHIFT);
    int cx1 = min(CELLS_X - 1, (RX0 + REG - 1 + half) >> CELL_SHIFT);
    int cy0 = max(0, (RY0 - half) >> CELL_SHIFT);
    int cy1 = min(CELLS_X - 1, (RY0 + REG - 1 + half) >> CELL_SHIFT);
    int ncx = cx1 - cx0 + 1;
    int ncells = ncx * (cy1 - cy0 + 1);
    int npairs = ncells * CAP;
    float ncx_rcp = __builtin_amdgcn_rcpf((float)ncx);
    int rounds = (npairs + 511) / 512;

    if (flat == 0) ncand_sh = 0;
    if (flat < ncells) {
        int cy = (int)(((float)flat + 0.5f) * ncx_rcp);    // flat <= 35: exact
        int cx = flat - cy * ncx;
        scnt[flat] = min(counts[(cy0 + cy) * CELLS_X + (cx0 + cx)], CAP);
    }
    __syncthreads();

    // ---- stage: coalesced bins loads gated by LDS counts, overlap prefilter,
    //      ballot-compacted append (one LDS atomic per wave per round) ----
    for (int rd = 0; rd < rounds; ++rd) {
        int pr = rd * 512 + flat;
        bool ok = false;
        float4 p = make_float4(0.f, 0.f, 0.f, 0.f);
        if (pr < npairs) {
            int c = pr / CAP;                    // constant divisor -> magic mul
            int s = pr - c * CAP;
            if (s < scnt[c]) {
                int cy = (int)(((float)c + 0.5f) * ncx_rcp);   // c <= 35: exact
                int cx = c - cy * ncx;
                int cell = (cy0 + cy) * CELLS_X + (cx0 + cx);
                p = bins[(size_t)cell * CAP + s];
                int cxi = (int)p.x, cyi = (int)p.y;
                ok = (cxi + half >= RX0 && cxi - half < RX0 + REG &&
                      cyi + half >= RY0 && cyi - half < RY0 + REG);
            }
        }
        unsigned long long m = __ballot(ok);
        if (m) {
            int leader = (int)__ffsll((unsigned long long)m) - 1;
            int base = 0;
            if (lane == leader) base = atomicAdd(&ncand_sh, __popcll(m));
            base = __shfl(base, leader);
            if (ok) {
                int pos = base + __popcll(m & ((1ull << lane) - 1));
                if (pos < CANDMAX) cand[pos] = p;
            }
        }
    }
    __syncthreads();
    int nc = min(ncand_sh, CANDMAX);
    int nch = (nc + CH - 1) / CH;

    // ---- K-chunked GEMM: C[r][c] = sum_k Af[r][k]*Bf[c][k] ----
    // wave handles output tiles t=wave and t+8: m-off=(t&3)*16, n-off=(t>>2)*16.
    // mfma_f32_16x16x32_f16 frags: A[m=lane&15][k=quad*8+j],
    // B[k=quad*8+j][n=lane&15]; C/D: col=lane&15, row=quad*4+reg.
    floatx4 acc0 = {0.f, 0.f, 0.f, 0.f};
    floatx4 acc1 = {0.f, 0.f, 0.f, 0.f};
    int m0 = (wave & 3) * 16,       n0 = (wave >> 2) * 16;
    int m1 = ((wave + 8) & 3) * 16, n1 = ((wave + 8) >> 2) * 16;
    int fr = lane & 15;             // frag spatial index
    int fk = (lane >> 4) * 8;       // frag k offset

    // build roles: waves 0-3 -> A (rows/y), waves 4-7 -> B (cols/x);
    // octet = wave&3 covers k sub-range [oct*8, oct*8+8). Lane owns spatial
    // coord `lane`; computes 8 k-values in regs, ONE ds_write_b128.
    int side = wave >> 2;           // 0 = A, 1 = B
    int oct = wave & 3;
    float dbase = (side ? (float)RX0 : (float)RY0) + (float)lane;

    for (int ci = 0; ci < nch; ++ci) {
        int b = ci & 1;
        int c0 = ci * CH + oct * 8;
        half8 hv;
        #pragma unroll
        for (int t = 0; t < 8; ++t) {
            int k = c0 + t;
            float val = 0.0f;
            if (k < nc) {
                float4 p = cand[k];              // wave-uniform -> broadcast
                float d = dbase - (side ? p.x : p.y);
                if (fabsf(d) <= halff) {
                    val = __expf(p.w * d * d);
                    if (side) val *= p.z;        // fold height into B
                }
            }
            hv[t] = (_Float16)val;
        }
        _Float16* dst = side ? &Bfb[b][lane * CH_PAD + oct * 8]
                             : &Afb[b][lane * CH_PAD + oct * 8];
        *(half8*)dst = hv;                       // 16 B aligned (80B rows)
        __syncthreads();                         // build(ci) -> mfma(ci); also
                                                 // fences mfma(ci-1) vs
                                                 // build(ci+1) buffer reuse
        half8 a0 = *(const half8*)&Afb[b][(m0 + fr) * CH_PAD + fk];
        half8 b0 = *(const half8*)&Bfb[b][(n0 + fr) * CH_PAD + fk];
        acc0 = __builtin_amdgcn_mfma_f32_16x16x32_f16(a0, b0, acc0, 0, 0, 0);
        half8 a1 = *(const half8*)&Afb[b][(m1 + fr) * CH_PAD + fk];
        half8 b1 = *(const half8*)&Bfb[b][(n1 + fr) * CH_PAD + fk];
        acc1 = __builtin_amdgcn_mfma_f32_16x16x32_f16(a1, b1, acc1, 0, 0, 0);
    }

    // ---- epilogue: background + store (C/D layout: col=lane&15, row=q*4+reg)
    int col = lane & 15;
    int qr = (lane >> 4) * 4;
    {
        size_t gx = (size_t)(RX0 + n0 + col);
        size_t gy = (size_t)(RY0 + m0 + qr);
        for (int r = 0; r < 4; ++r)
            out[(gy + r) * IMG_W + gx] = acc0[r] + 0.1f;
    }
    {
        size_t gx = (size_t)(RX0 + n1 + col);
        size_t gy = (size_t)(RY0 + m1 + qr);
        for (int r = 0; r < 4; ++r)
            out[(gy + r) * IMG_W + gx] = acc1[r] + 0.1f;
    }
}

extern "C" void kernel_launch(void* const* d_in, const int* in_sizes, int n_in,
                              void* d_out, int out_size, void* d_ws, size_t ws_size,
                              hipStream_t stream) {
    // inputs: 0:X 1:Y 2:pos_x 3:pos_y 4:height 5:width (X/Y unused: X[0,0]=Y[0,0]=0)
    const float* pos_x  = (const float*)d_in[2];
    const float* pos_y  = (const float*)d_in[3];
    const float* height = (const float*)d_in[4];
    const float* width  = (const float*)d_in[5];
    int P = in_sizes[2];
    float* out = (float*)d_out;
    char* ws = (char*)d_ws;

    // layout: [wmax pad16 | counts NCELL | bins NCELL*CAP*16]  (~5.3 MB total)
    unsigned int* wmax = (unsigned int*)ws;
    int* counts = (int*)(ws + 16);
    size_t bins_off = 16 + sizeof(int) * (size_t)NCELL;   // 65552, 16-aligned
    float4* bins = (float4*)(ws + bins_off);

    hipMemsetAsync(ws, 0, bins_off, stream);              // wmax + counts
    k_bin<<<(P + 255) / 256, 256, 0, stream>>>(pos_x, pos_y, height, width, P,
                                               counts, wmax, bins);
    dim3 grid(IMG_W / REG, IMG_H / REG), block(512);
    k_render<<<grid, block, 0, stream>>>(counts, bins, wmax, out);
}